// Round 1
// baseline (246.065 us; speedup 1.0000x reference)
//
#include <hip/hip_runtime.h>
#include <hip/hip_bf16.h>

typedef unsigned short ushort_t;
typedef __bf16 bf16x8 __attribute__((ext_vector_type(8)));
typedef float f32x4 __attribute__((ext_vector_type(4)));

__device__ __forceinline__ unsigned short f2bf(float f) {
    unsigned int u = __builtin_bit_cast(unsigned int, f);
    unsigned int r = u + 0x7FFFu + ((u >> 16) & 1u);
    return (unsigned short)(r >> 16);
}

__device__ __forceinline__ float bf2f(unsigned int bits16) {
    return __builtin_bit_cast(float, bits16 << 16);
}

__device__ __forceinline__ void gload_lds16(const void* g, void* l) {
    __builtin_amdgcn_global_load_lds(
        (__attribute__((address_space(1))) void*)(g),
        (__attribute__((address_space(3))) void*)(l), 16, 0, 0);
}

// ---------------- fp32 -> bf16 convert, 8 elems/thread ----------------
__global__ __launch_bounds__(256) void cvt_bf16_kernel(
    const float* __restrict__ in, unsigned short* __restrict__ out, int n8)
{
    int i = blockIdx.x * 256 + threadIdx.x;
    if (i >= n8) return;
    const float4* p = (const float4*)in + 2 * (long long)i;
    float4 a = p[0], b = p[1];
    uint4 o;
    o.x = (unsigned)f2bf(a.x) | ((unsigned)f2bf(a.y) << 16);
    o.y = (unsigned)f2bf(a.z) | ((unsigned)f2bf(a.w) << 16);
    o.z = (unsigned)f2bf(b.x) | ((unsigned)f2bf(b.y) << 16);
    o.w = (unsigned)f2bf(b.z) | ((unsigned)f2bf(b.w) << 16);
    ((uint4*)out)[i] = o;
}

// ---------------- bf16 GEMM, C = A[M,K] * B[N,K]^T ----------------
// m97-style: 128x128 tile, BK=32, 256 threads (4 waves 2x2, 64x64 each),
// global_load_lds width-16 staging, mfma_f32_16x16x32_bf16.
template <bool OUT_F32, bool TRANS>
__global__ __launch_bounds__(256) void gemm_bt(
    const unsigned short* __restrict__ A, const unsigned short* __restrict__ B,
    void* __restrict__ Cvoid, int M, int N, int K,
    long long sA, long long sB, long long sC, int ldc)
{
    __shared__ unsigned short sAt[128 * 32];
    __shared__ unsigned short sBt[128 * 32];
    const int z = blockIdx.z;
    A += (long long)z * sA;
    B += (long long)z * sB;

    const int tid  = threadIdx.x;
    const int lane = tid & 63;
    const int wave = tid >> 6;
    const int wr = wave >> 1, wc = wave & 1;     // 2x2 wave grid
    const int m0 = blockIdx.y * 128;
    const int n0 = blockIdx.x * 128;
    const int fl = lane & 15, fg = lane >> 4;    // fragment col / k-group

    f32x4 acc[4][4];
#pragma unroll
    for (int i = 0; i < 4; ++i)
#pragma unroll
        for (int j = 0; j < 4; ++j) acc[i][j] = (f32x4){0.f, 0.f, 0.f, 0.f};

    // staging geometry: flat in [0,512), each stages 8 contiguous bf16 (16B)
    const int flat0 = tid, flat1 = tid + 256;
    const int r0row = flat0 >> 2, r0k = (flat0 & 3) * 8;
    const int r1row = flat1 >> 2, r1k = (flat1 & 3) * 8;
    const unsigned short* A0 = A + (long long)(m0 + r0row) * K + r0k;
    const unsigned short* A1 = A + (long long)(m0 + r1row) * K + r1k;
    const unsigned short* B0 = B + (long long)(n0 + r0row) * K + r0k;
    const unsigned short* B1 = B + (long long)(n0 + r1row) * K + r1k;

    for (int k0 = 0; k0 < K; k0 += 32) {
        gload_lds16(A0 + k0, &sAt[flat0 * 8]);
        gload_lds16(A1 + k0, &sAt[flat1 * 8]);
        gload_lds16(B0 + k0, &sBt[flat0 * 8]);
        gload_lds16(B1 + k0, &sBt[flat1 * 8]);
        __syncthreads();

        bf16x8 af[4], bq[4];
#pragma unroll
        for (int mi = 0; mi < 4; ++mi)
            af[mi] = *(const bf16x8*)&sAt[(wr * 64 + mi * 16 + fl) * 32 + fg * 8];
#pragma unroll
        for (int ni = 0; ni < 4; ++ni)
            bq[ni] = *(const bf16x8*)&sBt[(wc * 64 + ni * 16 + fl) * 32 + fg * 8];
#pragma unroll
        for (int mi = 0; mi < 4; ++mi)
#pragma unroll
            for (int ni = 0; ni < 4; ++ni)
                acc[mi][ni] = __builtin_amdgcn_mfma_f32_16x16x32_bf16(
                    af[mi], bq[ni], acc[mi][ni], 0, 0, 0);
        __syncthreads();
    }

    // epilogue: C/D layout col = lane&15, row = (lane>>4)*4 + j
    if constexpr (OUT_F32) {
        float* C = (float*)Cvoid + (long long)z * sC;
#pragma unroll
        for (int mi = 0; mi < 4; ++mi)
#pragma unroll
            for (int ni = 0; ni < 4; ++ni)
#pragma unroll
                for (int j = 0; j < 4; ++j) {
                    int grow = m0 + wr * 64 + mi * 16 + fg * 4 + j;
                    int gcol = n0 + wc * 64 + ni * 16 + fl;
                    long long addr = TRANS ? ((long long)gcol * ldc + grow)
                                           : ((long long)grow * ldc + gcol);
                    C[addr] = acc[mi][ni][j];
                }
    } else {
        unsigned short* C = (unsigned short*)Cvoid + (long long)z * sC;
#pragma unroll
        for (int mi = 0; mi < 4; ++mi)
#pragma unroll
            for (int ni = 0; ni < 4; ++ni)
#pragma unroll
                for (int j = 0; j < 4; ++j) {
                    int grow = m0 + wr * 64 + mi * 16 + fg * 4 + j;
                    int gcol = n0 + wc * 64 + ni * 16 + fl;
                    long long addr = TRANS ? ((long long)gcol * ldc + grow)
                                           : ((long long)grow * ldc + gcol);
                    C[addr] = f2bf(acc[mi][ni][j]);
                }
    }
}

// ---------------- row softmax over 2048 bf16, in place, scale 1/32 ----------------
__global__ __launch_bounds__(256) void softmax_rows(unsigned short* __restrict__ S)
{
    const long long row = blockIdx.x;
    unsigned short* p = S + row * 2048;
    const int tid = threadIdx.x;
    const int lane = tid & 63, wave = tid >> 6;

    uint4 r4 = ((const uint4*)p)[tid];
    unsigned u[4] = {r4.x, r4.y, r4.z, r4.w};
    float v[8];
    const float scale = 1.0f / 32.0f;
#pragma unroll
    for (int i = 0; i < 4; ++i) {
        v[2 * i]     = bf2f(u[i] & 0xFFFFu) * scale;
        v[2 * i + 1] = __builtin_bit_cast(float, u[i] & 0xFFFF0000u) * scale;
    }
    float mx = v[0];
#pragma unroll
    for (int i = 1; i < 8; ++i) mx = fmaxf(mx, v[i]);
#pragma unroll
    for (int off = 32; off >= 1; off >>= 1) mx = fmaxf(mx, __shfl_xor(mx, off, 64));

    __shared__ float redmax[4], redsum[4];
    if (lane == 0) redmax[wave] = mx;
    __syncthreads();
    mx = fmaxf(fmaxf(redmax[0], redmax[1]), fmaxf(redmax[2], redmax[3]));

    float s = 0.f;
#pragma unroll
    for (int i = 0; i < 8; ++i) { v[i] = __expf(v[i] - mx); s += v[i]; }
#pragma unroll
    for (int off = 32; off >= 1; off >>= 1) s += __shfl_xor(s, off, 64);
    if (lane == 0) redsum[wave] = s;
    __syncthreads();
    s = redsum[0] + redsum[1] + redsum[2] + redsum[3];
    float inv = 1.0f / s;

    uint4 o;
    unsigned ov[4];
#pragma unroll
    for (int i = 0; i < 4; ++i)
        ov[i] = (unsigned)f2bf(v[2 * i] * inv) |
                ((unsigned)f2bf(v[2 * i + 1] * inv) << 16);
    o.x = ov[0]; o.y = ov[1]; o.z = ov[2]; o.w = ov[3];
    ((uint4*)p)[tid] = o;
}

extern "C" void kernel_launch(void* const* d_in, const int* in_sizes, int n_in,
                              void* d_out, int out_size, void* d_ws, size_t ws_size,
                              hipStream_t stream) {
    const float* x  = (const float*)d_in[0];   // [4,2048,1024]
    const float* Wq = (const float*)d_in[1];   // [1024,1024]
    const float* Wk = (const float*)d_in[2];
    const float* Wv = (const float*)d_in[3];
    float* out = (float*)d_out;                // [4,2048,1024] fp32

    const int B = 4, S = 2048, D = 1024;
    const long long MS = (long long)B * S;     // 8192

    // workspace layout (elements of ushort/bf16)
    unsigned short* xb  = (unsigned short*)d_ws;            // 8192*1024
    unsigned short* wqb = xb  + MS * D;                     // 1024*1024
    unsigned short* wkb = wqb + D * D;
    unsigned short* wvb = wkb + D * D;
    unsigned short* q   = wvb + D * D;                      // 8192*1024
    unsigned short* kk  = q   + MS * D;                     // 8192*1024
    unsigned short* vT  = kk  + MS * D;                     // 4 * [1024,2048]
    unsigned short* Sc  = vT  + MS * D;                     // 4 * [2048,2048]
    size_t need = (size_t)2 * (MS * D * 4 + 3 * D * D + (long long)B * S * S);
    if (ws_size < need) return;  // insufficient workspace

    // 1) converts
    cvt_bf16_kernel<<<(MS * D / 8 + 255) / 256, 256, 0, stream>>>(x, xb, (int)(MS * D / 8));
    cvt_bf16_kernel<<<(D * D / 8 + 255) / 256, 256, 0, stream>>>(Wq, wqb, D * D / 8);
    cvt_bf16_kernel<<<(D * D / 8 + 255) / 256, 256, 0, stream>>>(Wk, wkb, D * D / 8);
    cvt_bf16_kernel<<<(D * D / 8 + 255) / 256, 256, 0, stream>>>(Wv, wvb, D * D / 8);

    // 2) Q = x*Wq^T, K = x*Wk^T  (all batches as one [8192,1024] GEMM)
    gemm_bt<false, false><<<dim3(D / 128, MS / 128, 1), 256, 0, stream>>>(
        xb, wqb, q, (int)MS, D, D, 0, 0, 0, D);
    gemm_bt<false, false><<<dim3(D / 128, MS / 128, 1), 256, 0, stream>>>(
        xb, wkb, kk, (int)MS, D, D, 0, 0, 0, D);
    // V stored transposed per batch: vT[b][e][s]
    gemm_bt<false, true><<<dim3(D / 128, S / 128, B), 256, 0, stream>>>(
        xb, wvb, vT, S, D, D, (long long)S * D, 0, (long long)D * S, S);

    // 3) scores S = q_b * k_b^T (bf16, unscaled)
    gemm_bt<false, false><<<dim3(S / 128, S / 128, B), 256, 0, stream>>>(
        q, kk, Sc, S, S, D, (long long)S * D, (long long)S * D, (long long)S * S, S);

    // 4) softmax rows (applies 1/32 scale)
    softmax_rows<<<B * S, 256, 0, stream>>>(Sc);

    // 5) out = P_b * V_b   (= P * vT^T, fp32 out)
    gemm_bt<true, false><<<dim3(D / 128, S / 128, B), 256, 0, stream>>>(
        Sc, vT, out, S, D, S, (long long)S * S, (long long)D * S, (long long)S * D, D);
}

// Round 2
// 228.775 us; speedup vs baseline: 1.0756x; 1.0756x over previous
//
#include <hip/hip_runtime.h>
#include <hip/hip_bf16.h>

typedef unsigned short u16;
typedef __bf16 bf16x8 __attribute__((ext_vector_type(8)));
typedef float f32x4 __attribute__((ext_vector_type(4)));

#define MEMF() asm volatile("" ::: "memory")

__device__ __forceinline__ u16 f2bf(float f) {
    unsigned int u = __builtin_bit_cast(unsigned int, f);
    unsigned int r = u + 0x7FFFu + ((u >> 16) & 1u);
    return (u16)(r >> 16);
}

__device__ __forceinline__ float bf2f(unsigned int bits16) {
    return __builtin_bit_cast(float, bits16 << 16);
}

__device__ __forceinline__ void gload_lds16(const void* g, void* l) {
    __builtin_amdgcn_global_load_lds(
        (__attribute__((address_space(1))) void*)(g),
        (__attribute__((address_space(3))) void*)(l), 16, 0, 0);
}

// ---------------- fp32 -> bf16 convert, 8 elems/thread ----------------
__global__ __launch_bounds__(256) void cvt_bf16_kernel(
    const float* __restrict__ in, u16* __restrict__ out, int n8)
{
    int i = blockIdx.x * 256 + threadIdx.x;
    if (i >= n8) return;
    const float4* p = (const float4*)in + 2 * (long long)i;
    float4 a = p[0], b = p[1];
    uint4 o;
    o.x = (unsigned)f2bf(a.x) | ((unsigned)f2bf(a.y) << 16);
    o.y = (unsigned)f2bf(a.z) | ((unsigned)f2bf(a.w) << 16);
    o.z = (unsigned)f2bf(b.x) | ((unsigned)f2bf(b.y) << 16);
    o.w = (unsigned)f2bf(b.z) | ((unsigned)f2bf(b.w) << 16);
    ((uint4*)out)[i] = o;
}

// ---------------- 8-phase 256x256 bf16 GEMM, C = A[M,K] * B[N,K]^T ----------------
// 512 threads = 8 waves (2M x 4N), per-wave 128x64 output, BK=64, 128KiB dbuf LDS.
// LDS layout per 256x64 tile: [R=16][G=8][r=16][8 elems] (R=16-row block, G=8-col group)
//  -> every wave ds_read_b128 covers 64 consecutive 16B slots (conflict-free),
//  -> global_load_lds writes are linear in tid (layout "swizzle" folded into gsrc addr).
// Phases per K-tile: p1 read A(lo)+B(lo), MFMA q(0,0); p2 read B(hi), q(0,1);
//  p3 read A(hi) + stage B-halves of kt+2, q(1,0); p4 stage A-halves of kt+2, q(1,1),
//  vmcnt(8) (tile kt+1 landed, kt+2's 8 loads stay in flight), barrier.
template <bool OUT_F32>
__global__ __launch_bounds__(512, 2) void gemm8p(
    const u16* __restrict__ A, const u16* __restrict__ B, void* __restrict__ Cv,
    int lda, int ldb, int ldc, int K,
    long long sAz, long long sBz, long long sCz)
{
    extern __shared__ u16 lds[];   // [buf0 A][buf1 A][buf0 B][buf1 B] 16384 els each
    const int z = blockIdx.z;
    A += (long long)z * sAz;
    B += (long long)z * sBz;

    const int tid  = threadIdx.x;
    const int lane = tid & 63;
    const int wave = tid >> 6;
    const int wr = wave >> 2, wc = wave & 3;
    const int m0 = blockIdx.y << 8, n0 = blockIdx.x << 8;
    const int NT = K >> 6;                 // K-tiles of 64 (NT >= 3 assumed)

    // staging geometry: thread tid stages 8 contiguous bf16 (16B).
    // LDS slot tid -> logical (row = (tid>>7)*16 + (tid&15), colgroup = (tid>>4)&7)
    const int slot_r = ((tid >> 7) << 4) | (tid & 15);
    const int g8 = (tid >> 4) & 7;
    const u16* gA = A + (long long)(m0 + slot_r) * lda + g8 * 8;
    const u16* gB = B + (long long)(n0 + slot_r) * ldb + g8 * 8;
    u16* ldsSt = lds + tid * 8;

    auto stA = [&](int buf, int kt, int h) {
        const u16* s = gA + (long long)(h * 128) * lda + kt * 64;
        u16* d = ldsSt + buf * 16384 + h * 8192;
        gload_lds16(s, d);
        gload_lds16(s + (long long)64 * lda, d + 4096);
    };
    auto stB = [&](int buf, int kt, int h) {
        const u16* s = gB + (long long)(h * 128) * ldb + kt * 64;
        u16* d = ldsSt + 32768 + buf * 16384 + h * 8192;
        gload_lds16(s, d);
        gload_lds16(s + (long long)64 * ldb, d + 4096);
    };

    f32x4 acc[8][4] = {};

    // prologue: tile0 -> buf0, tile1 -> buf1; wait tile0 (8 newest stay in flight)
    stA(0, 0, 0); stA(0, 0, 1); stB(0, 0, 0); stB(0, 0, 1);
    stA(1, 1, 0); stA(1, 1, 1); stB(1, 1, 0); stB(1, 1, 1);
    asm volatile("s_waitcnt vmcnt(8)" ::: "memory");
    __builtin_amdgcn_s_barrier();
    MEMF();

    bf16x8 av[4][2], b0[2][2], b1[2][2];

    for (int kt = 0; kt < NT; ++kt) {
        const int cur = kt & 1;
        const u16* sAc = lds + cur * 16384 + lane * 8;
        const u16* sBc = lds + 32768 + cur * 16384 + lane * 8;

        // ---------- phase 1: read A-lo + B-lo frags; MFMA quadrant (0,0) ----------
#pragma unroll
        for (int mi = 0; mi < 4; ++mi)
#pragma unroll
            for (int kk = 0; kk < 2; ++kk)
                av[mi][kk] = *(const bf16x8*)(sAc + ((wr * 8 + mi) * 8 + kk * 4) * 128);
#pragma unroll
        for (int ni = 0; ni < 2; ++ni)
#pragma unroll
            for (int kk = 0; kk < 2; ++kk)
                b0[ni][kk] = *(const bf16x8*)(sBc + ((wc * 4 + ni) * 8 + kk * 4) * 128);
        MEMF(); __builtin_amdgcn_s_barrier(); MEMF();
        __builtin_amdgcn_sched_barrier(0);
        __builtin_amdgcn_s_setprio(1);
#pragma unroll
        for (int kk = 0; kk < 2; ++kk)
#pragma unroll
            for (int mi = 0; mi < 4; ++mi)
#pragma unroll
                for (int ni = 0; ni < 2; ++ni)
                    acc[mi][ni] = __builtin_amdgcn_mfma_f32_16x16x32_bf16(
                        av[mi][kk], b0[ni][kk], acc[mi][ni], 0, 0, 0);
        __builtin_amdgcn_s_setprio(0);
        __builtin_amdgcn_sched_barrier(0);
        MEMF(); __builtin_amdgcn_s_barrier(); MEMF();

        // ---------- phase 2: read B-hi frags; MFMA quadrant (0,1) ----------
#pragma unroll
        for (int ni = 0; ni < 2; ++ni)
#pragma unroll
            for (int kk = 0; kk < 2; ++kk)
                b1[ni][kk] = *(const bf16x8*)(sBc + ((wc * 4 + 2 + ni) * 8 + kk * 4) * 128);
        MEMF(); __builtin_amdgcn_s_barrier(); MEMF();
        __builtin_amdgcn_sched_barrier(0);
        __builtin_amdgcn_s_setprio(1);
#pragma unroll
        for (int kk = 0; kk < 2; ++kk)
#pragma unroll
            for (int mi = 0; mi < 4; ++mi)
#pragma unroll
                for (int ni = 0; ni < 2; ++ni)
                    acc[mi][2 + ni] = __builtin_amdgcn_mfma_f32_16x16x32_bf16(
                        av[mi][kk], b1[ni][kk], acc[mi][2 + ni], 0, 0, 0);
        __builtin_amdgcn_s_setprio(0);
        __builtin_amdgcn_sched_barrier(0);
        MEMF(); __builtin_amdgcn_s_barrier(); MEMF();

        // ---------- phase 3: read A-hi frags; stage kt+2 B-halves; MFMA (1,0) ----------
#pragma unroll
        for (int mi = 0; mi < 4; ++mi)
#pragma unroll
            for (int kk = 0; kk < 2; ++kk)
                av[mi][kk] = *(const bf16x8*)(sAc + ((wr * 8 + 4 + mi) * 8 + kk * 4) * 128);
        if (kt + 2 < NT) { stB(cur, kt + 2, 0); stB(cur, kt + 2, 1); }
        MEMF(); __builtin_amdgcn_s_barrier(); MEMF();
        __builtin_amdgcn_sched_barrier(0);
        __builtin_amdgcn_s_setprio(1);
#pragma unroll
        for (int kk = 0; kk < 2; ++kk)
#pragma unroll
            for (int mi = 0; mi < 4; ++mi)
#pragma unroll
                for (int ni = 0; ni < 2; ++ni)
                    acc[4 + mi][ni] = __builtin_amdgcn_mfma_f32_16x16x32_bf16(
                        av[mi][kk], b0[ni][kk], acc[4 + mi][ni], 0, 0, 0);
        __builtin_amdgcn_s_setprio(0);
        __builtin_amdgcn_sched_barrier(0);
        MEMF(); __builtin_amdgcn_s_barrier(); MEMF();

        // ---------- phase 4: stage kt+2 A-halves; MFMA (1,1); counted vmcnt ----------
        if (kt + 2 < NT) { stA(cur, kt + 2, 0); stA(cur, kt + 2, 1); }
        MEMF(); __builtin_amdgcn_s_barrier(); MEMF();
        __builtin_amdgcn_sched_barrier(0);
        __builtin_amdgcn_s_setprio(1);
#pragma unroll
        for (int kk = 0; kk < 2; ++kk)
#pragma unroll
            for (int mi = 0; mi < 4; ++mi)
#pragma unroll
                for (int ni = 0; ni < 2; ++ni)
                    acc[4 + mi][2 + ni] = __builtin_amdgcn_mfma_f32_16x16x32_bf16(
                        av[mi][kk], b1[ni][kk], acc[4 + mi][2 + ni], 0, 0, 0);
        __builtin_amdgcn_s_setprio(0);
        __builtin_amdgcn_sched_barrier(0);
        if (kt + 2 < NT) {
            asm volatile("s_waitcnt vmcnt(8)" ::: "memory");   // kt+1 landed, kt+2 in flight
        } else if (kt + 1 < NT) {
            asm volatile("s_waitcnt vmcnt(0)" ::: "memory");   // tail: drain last tile
        }
        MEMF(); __builtin_amdgcn_s_barrier(); MEMF();
    }

    // ---------- epilogue: C/D frag layout col = lane&15, row = (lane>>4)*4+j ----------
    const int fl = lane & 15, fg = lane >> 4;
    const int er0 = m0 + wr * 128 + fg * 4;
    const int ec0 = n0 + wc * 64 + fl;
    if constexpr (OUT_F32) {
        float* C = (float*)Cv + (long long)z * sCz;
#pragma unroll
        for (int mi = 0; mi < 8; ++mi)
#pragma unroll
            for (int ni = 0; ni < 4; ++ni)
#pragma unroll
                for (int j = 0; j < 4; ++j)
                    C[(long long)(er0 + mi * 16 + j) * ldc + ec0 + ni * 16] = acc[mi][ni][j];
    } else {
        u16* C = (u16*)Cv + (long long)z * sCz;
#pragma unroll
        for (int mi = 0; mi < 8; ++mi)
#pragma unroll
            for (int ni = 0; ni < 4; ++ni)
#pragma unroll
                for (int j = 0; j < 4; ++j)
                    C[(long long)(er0 + mi * 16 + j) * ldc + ec0 + ni * 16] = f2bf(acc[mi][ni][j]);
    }
}

// ---------------- row softmax over 2048 bf16, in place, scale 1/32 ----------------
__global__ __launch_bounds__(256) void softmax_rows(u16* __restrict__ S)
{
    const long long row = blockIdx.x;
    u16* p = S + row * 2048;
    const int tid = threadIdx.x;
    const int lane = tid & 63, wave = tid >> 6;

    uint4 r4 = ((const uint4*)p)[tid];
    unsigned u[4] = {r4.x, r4.y, r4.z, r4.w};
    float v[8];
    const float scale = 1.0f / 32.0f;
#pragma unroll
    for (int i = 0; i < 4; ++i) {
        v[2 * i]     = bf2f(u[i] & 0xFFFFu) * scale;
        v[2 * i + 1] = __builtin_bit_cast(float, u[i] & 0xFFFF0000u) * scale;
    }
    float mx = v[0];
#pragma unroll
    for (int i = 1; i < 8; ++i) mx = fmaxf(mx, v[i]);
#pragma unroll
    for (int off = 32; off >= 1; off >>= 1) mx = fmaxf(mx, __shfl_xor(mx, off, 64));

    __shared__ float redmax[4], redsum[4];
    if (lane == 0) redmax[wave] = mx;
    __syncthreads();
    mx = fmaxf(fmaxf(redmax[0], redmax[1]), fmaxf(redmax[2], redmax[3]));

    float s = 0.f;
#pragma unroll
    for (int i = 0; i < 8; ++i) { v[i] = __expf(v[i] - mx); s += v[i]; }
#pragma unroll
    for (int off = 32; off >= 1; off >>= 1) s += __shfl_xor(s, off, 64);
    if (lane == 0) redsum[wave] = s;
    __syncthreads();
    s = redsum[0] + redsum[1] + redsum[2] + redsum[3];
    float inv = 1.0f / s;

    uint4 o;
    unsigned ov[4];
#pragma unroll
    for (int i = 0; i < 4; ++i)
        ov[i] = (unsigned)f2bf(v[2 * i] * inv) |
                ((unsigned)f2bf(v[2 * i + 1] * inv) << 16);
    o.x = ov[0]; o.y = ov[1]; o.z = ov[2]; o.w = ov[3];
    ((uint4*)p)[tid] = o;
}

extern "C" void kernel_launch(void* const* d_in, const int* in_sizes, int n_in,
                              void* d_out, int out_size, void* d_ws, size_t ws_size,
                              hipStream_t stream) {
    const float* x  = (const float*)d_in[0];   // [4,2048,1024]
    const float* Wq = (const float*)d_in[1];   // [1024,1024]
    const float* Wk = (const float*)d_in[2];
    const float* Wv = (const float*)d_in[3];
    float* out = (float*)d_out;                // [4,2048,1024] fp32

    const int B = 4, S = 2048, D = 1024;
    const long long MS = (long long)B * S;     // 8192

    // workspace layout (bf16 elements); Sc overlays xb (xb dead after GEMM2)
    u16* Sc  = (u16*)d_ws;                     // 4*2048*2048 = 16.78M els
    u16* xb  = Sc;                             // 8192*1024   =  8.39M els (first half)
    u16* wqk = Sc  + (long long)B * S * S;     // 2*1024*1024
    u16* wvb = wqk + 2 * D * D;                // 1024*1024
    u16* qk  = wvb + D * D;                    // 8192*2048
    u16* vT  = qk  + MS * 2 * D;               // 1024*8192
    size_t need = (size_t)2 * ((long long)B * S * S + 3 * D * D + MS * 2 * D + MS * D);
    if (ws_size < need) return;

    hipFuncSetAttribute(reinterpret_cast<const void*>(&gemm8p<false>),
                        hipFuncAttributeMaxDynamicSharedMemorySize, 131072);
    hipFuncSetAttribute(reinterpret_cast<const void*>(&gemm8p<true>),
                        hipFuncAttributeMaxDynamicSharedMemorySize, 131072);

    // 1) converts
    cvt_bf16_kernel<<<(int)(MS * D / 8 / 256), 256, 0, stream>>>(x, xb, (int)(MS * D / 8));
    cvt_bf16_kernel<<<D * D / 8 / 256, 256, 0, stream>>>(Wq, wqk, D * D / 8);
    cvt_bf16_kernel<<<D * D / 8 / 256, 256, 0, stream>>>(Wk, wqk + D * D, D * D / 8);
    cvt_bf16_kernel<<<D * D / 8 / 256, 256, 0, stream>>>(Wv, wvb, D * D / 8);

    // 2) qk[8192][2048] = xb * [Wq;Wk]^T   (grid 8x32 = 256 blocks)
    gemm8p<false><<<dim3(2 * D / 256, MS / 256, 1), 512, 131072, stream>>>(
        xb, wqk, qk, D, D, 2 * D, D, 0, 0, 0);

    // 3) vT[1024][8192] = Wv * xb^T        (grid 32x4 = 128 blocks)
    gemm8p<false><<<dim3(MS / 256, D / 256, 1), 512, 131072, stream>>>(
        wvb, xb, vT, D, D, (int)MS, D, 0, 0, 0);

    // 4) scores Sc_b = q_b * k_b^T  (q = qk cols 0..1023, k = cols 1024..2047)
    gemm8p<false><<<dim3(S / 256, S / 256, B), 512, 131072, stream>>>(
        qk, qk + D, Sc, 2 * D, 2 * D, S, D,
        (long long)S * 2 * D, (long long)S * 2 * D, (long long)S * S);

    // 5) softmax rows (applies 1/32 scale)
    softmax_rows<<<(int)(B * S), 256, 0, stream>>>(Sc);

    // 6) out_b = P_b * vT_b^T  (fp32 out; vT batch offset = z*2048 cols)
    gemm8p<true><<<dim3(D / 256, S / 256, B), 512, 131072, stream>>>(
        Sc, vT, out, S, (int)MS, D, S,
        (long long)S * S, (long long)S, (long long)S * D);
}

// Round 3
// 197.146 us; speedup vs baseline: 1.2481x; 1.1604x over previous
//
#include <hip/hip_runtime.h>
#include <hip/hip_bf16.h>

typedef unsigned short u16;
typedef __bf16 bf16x8 __attribute__((ext_vector_type(8)));
typedef float f32x4 __attribute__((ext_vector_type(4)));

#define MEMF() asm volatile("" ::: "memory")

__device__ __forceinline__ u16 f2bf(float f) {
    unsigned int u = __builtin_bit_cast(unsigned int, f);
    unsigned int r = u + 0x7FFFu + ((u >> 16) & 1u);
    return (u16)(r >> 16);
}

__device__ __forceinline__ float bf2f(unsigned int bits16) {
    return __builtin_bit_cast(float, bits16 << 16);
}

__device__ __forceinline__ void gload_lds16(const u16* g, u16* l) {
    __builtin_amdgcn_global_load_lds(
        (const __attribute__((address_space(1))) void*)(g),
        (__attribute__((address_space(3))) void*)(l), 16, 0, 0);
}

// ---------------- fp32 -> bf16 convert, 8 elems/thread ----------------
__global__ __launch_bounds__(256) void cvt_bf16_kernel(
    const float* __restrict__ in, u16* __restrict__ out, int n8)
{
    int i = blockIdx.x * 256 + threadIdx.x;
    if (i >= n8) return;
    const float4* p = (const float4*)in + 2 * (long long)i;
    float4 a = p[0], b = p[1];
    uint4 o;
    o.x = (unsigned)f2bf(a.x) | ((unsigned)f2bf(a.y) << 16);
    o.y = (unsigned)f2bf(a.z) | ((unsigned)f2bf(a.w) << 16);
    o.z = (unsigned)f2bf(b.x) | ((unsigned)f2bf(b.y) << 16);
    o.w = (unsigned)f2bf(b.z) | ((unsigned)f2bf(b.w) << 16);
    ((uint4*)out)[i] = o;
}

// ------- 2-barrier counted-vmcnt bf16 GEMM, C = A[M,K] * B[N,K]^T -------
// BM=256 fixed, BN template (256 or 128), BK=64, 512 threads = 8 waves (2M x 4N).
// Per-wave output 128 x (BN/4). LDS subtiled [R][G=8][r=16][8el]: ds_read_b128
// conflict-free, global_load_lds linear in tid (layout folded into gsrc addr).
// Per K-tile: {frag reads + 64*(BN/256) MFMAs with compiler-scheduled partial
// lgkmcnt} barrier {stage kt+2 -> cur buf} vmcnt(LOADS) barrier.
// Stages issued a full iteration before their wait -> HBM latency hidden.
template <int BN, bool OUT_F32>
__global__ __launch_bounds__(512, 2) void gemm2p(
    const u16* __restrict__ A, const u16* __restrict__ B, void* __restrict__ Cv,
    int lda, int ldb, int ldc, int K,
    long long sAz, long long sBz, long long sCz)
{
    constexpr int NF = BN / 64;        // n-frags per wave (4 or 2)
    constexpr int NH = NF / 2;         // n-frags per B-half (2 or 1)
    constexpr int BLOADS = BN / 64;    // B gload_lds per thread per K-tile
    constexpr int BNK = BN * 64;       // B buffer elems

    extern __shared__ u16 lds[];       // [A buf0 16384][A buf1 16384][B buf0 BNK][B buf1 BNK]
    u16* ldsB = lds + 32768;

    const int z = blockIdx.z;
    A += (long long)z * sAz;
    B += (long long)z * sBz;

    const int tid  = threadIdx.x;
    const int lane = tid & 63;
    const int wave = tid >> 6;
    const int wr = wave >> 2, wc = wave & 3;
    const int m0 = blockIdx.y << 8, n0 = blockIdx.x * BN;
    const int NT = K >> 6;

    // staging: slot s stages 8 contiguous bf16; logical row=((s>>7)<<4)|(s&15), colgrp=(s>>4)&7
    const u16* gAp[4];
    const u16* gBp[BLOADS];
#pragma unroll
    for (int i = 0; i < 4; ++i) {
        int s = tid + i * 512, row = ((s >> 7) << 4) | (s & 15), g = (s >> 4) & 7;
        gAp[i] = A + (long long)(m0 + row) * lda + g * 8;
    }
#pragma unroll
    for (int i = 0; i < BLOADS; ++i) {
        int s = tid + i * 512, row = ((s >> 7) << 4) | (s & 15), g = (s >> 4) & 7;
        gBp[i] = B + (long long)(n0 + row) * ldb + g * 8;
    }

    auto stage = [&](int kt, int buf) {
#pragma unroll
        for (int i = 0; i < 4; ++i)
            gload_lds16(gAp[i] + (long long)kt * 64, lds + buf * 16384 + (tid + i * 512) * 8);
#pragma unroll
        for (int i = 0; i < BLOADS; ++i)
            gload_lds16(gBp[i] + (long long)kt * 64, ldsB + buf * BNK + (tid + i * 512) * 8);
    };

    f32x4 acc[8][NF] = {};

    // prologue: tile0 -> buf0, tile1 -> buf1; wait tile0 only
    stage(0, 0);
    stage(1, 1);
    if constexpr (BN == 256) asm volatile("s_waitcnt vmcnt(8)" ::: "memory");
    else                     asm volatile("s_waitcnt vmcnt(6)" ::: "memory");
    __builtin_amdgcn_s_barrier();
    MEMF();

    for (int kt = 0; kt < NT; ++kt) {
        const int cur = kt & 1;
        const u16* sAc = lds  + cur * 16384 + lane * 8;
        const u16* sBc = ldsB + cur * BNK   + lane * 8;

        bf16x8 a_[4][2], b0[NH][2], b1[NH][2];
        // A low-half frags + all B frags
#pragma unroll
        for (int mi = 0; mi < 4; ++mi)
#pragma unroll
            for (int kk = 0; kk < 2; ++kk)
                a_[mi][kk] = *(const bf16x8*)(sAc + ((wr * 8 + mi) * 8 + kk * 4) * 128);
#pragma unroll
        for (int ni = 0; ni < NH; ++ni)
#pragma unroll
            for (int kk = 0; kk < 2; ++kk) {
                b0[ni][kk] = *(const bf16x8*)(sBc + ((wc * NF + ni) * 8 + kk * 4) * 128);
                b1[ni][kk] = *(const bf16x8*)(sBc + ((wc * NF + NH + ni) * 8 + kk * 4) * 128);
            }
        // rows 0..63 of wave tile
#pragma unroll
        for (int kk = 0; kk < 2; ++kk)
#pragma unroll
            for (int mi = 0; mi < 4; ++mi) {
#pragma unroll
                for (int ni = 0; ni < NH; ++ni)
                    acc[mi][ni] = __builtin_amdgcn_mfma_f32_16x16x32_bf16(
                        a_[mi][kk], b0[ni][kk], acc[mi][ni], 0, 0, 0);
#pragma unroll
                for (int ni = 0; ni < NH; ++ni)
                    acc[mi][NH + ni] = __builtin_amdgcn_mfma_f32_16x16x32_bf16(
                        a_[mi][kk], b1[ni][kk], acc[mi][NH + ni], 0, 0, 0);
            }
        // A high-half frags
#pragma unroll
        for (int mi = 0; mi < 4; ++mi)
#pragma unroll
            for (int kk = 0; kk < 2; ++kk)
                a_[mi][kk] = *(const bf16x8*)(sAc + ((wr * 8 + 4 + mi) * 8 + kk * 4) * 128);
        // rows 64..127
#pragma unroll
        for (int kk = 0; kk < 2; ++kk)
#pragma unroll
            for (int mi = 0; mi < 4; ++mi) {
#pragma unroll
                for (int ni = 0; ni < NH; ++ni)
                    acc[4 + mi][ni] = __builtin_amdgcn_mfma_f32_16x16x32_bf16(
                        a_[mi][kk], b0[ni][kk], acc[4 + mi][ni], 0, 0, 0);
#pragma unroll
                for (int ni = 0; ni < NH; ++ni)
                    acc[4 + mi][NH + ni] = __builtin_amdgcn_mfma_f32_16x16x32_bf16(
                        a_[mi][kk], b1[ni][kk], acc[4 + mi][NH + ni], 0, 0, 0);
            }

        MEMF();
        __builtin_amdgcn_s_barrier();          // all waves done reading buf cur
        if (kt + 2 < NT) {
            stage(kt + 2, cur);                // overwrite cur; wait kt+1 only
            if constexpr (BN == 256) asm volatile("s_waitcnt vmcnt(8)" ::: "memory");
            else                     asm volatile("s_waitcnt vmcnt(6)" ::: "memory");
        } else {
            asm volatile("s_waitcnt vmcnt(0)" ::: "memory");  // tail drain
        }
        __builtin_amdgcn_s_barrier();          // staged tile visible to all
        MEMF();
    }

    // epilogue: C/D frag layout col = lane&15, row = (lane>>4)*4+j
    const int fl = lane & 15, fg = lane >> 4;
    const int er0 = m0 + wr * 128 + fg * 4;
    const int ec0 = n0 + wc * (NF * 16) + fl;
    if constexpr (OUT_F32) {
        float* C = (float*)Cv + (long long)z * sCz;
#pragma unroll
        for (int mi = 0; mi < 8; ++mi)
#pragma unroll
            for (int ni = 0; ni < NF; ++ni)
#pragma unroll
                for (int j = 0; j < 4; ++j)
                    C[(long long)(er0 + mi * 16 + j) * ldc + ec0 + ni * 16] = acc[mi][ni][j];
    } else {
        u16* C = (u16*)Cv + (long long)z * sCz;
#pragma unroll
        for (int mi = 0; mi < 8; ++mi)
#pragma unroll
            for (int ni = 0; ni < NF; ++ni)
#pragma unroll
                for (int j = 0; j < 4; ++j)
                    C[(long long)(er0 + mi * 16 + j) * ldc + ec0 + ni * 16] = f2bf(acc[mi][ni][j]);
    }
}

// ---------------- row softmax over 2048 bf16, in place, scale 1/32 ----------------
__global__ __launch_bounds__(256) void softmax_rows(u16* __restrict__ S)
{
    const long long row = blockIdx.x;
    u16* p = S + row * 2048;
    const int tid = threadIdx.x;
    const int lane = tid & 63, wave = tid >> 6;

    uint4 r4 = ((const uint4*)p)[tid];
    unsigned u[4] = {r4.x, r4.y, r4.z, r4.w};
    float v[8];
    const float scale = 1.0f / 32.0f;
#pragma unroll
    for (int i = 0; i < 4; ++i) {
        v[2 * i]     = bf2f(u[i] & 0xFFFFu) * scale;
        v[2 * i + 1] = __builtin_bit_cast(float, u[i] & 0xFFFF0000u) * scale;
    }
    float mx = v[0];
#pragma unroll
    for (int i = 1; i < 8; ++i) mx = fmaxf(mx, v[i]);
#pragma unroll
    for (int off = 32; off >= 1; off >>= 1) mx = fmaxf(mx, __shfl_xor(mx, off, 64));

    __shared__ float redmax[4], redsum[4];
    if (lane == 0) redmax[wave] = mx;
    __syncthreads();
    mx = fmaxf(fmaxf(redmax[0], redmax[1]), fmaxf(redmax[2], redmax[3]));

    float s = 0.f;
#pragma unroll
    for (int i = 0; i < 8; ++i) { v[i] = __expf(v[i] - mx); s += v[i]; }
#pragma unroll
    for (int off = 32; off >= 1; off >>= 1) s += __shfl_xor(s, off, 64);
    if (lane == 0) redsum[wave] = s;
    __syncthreads();
    s = redsum[0] + redsum[1] + redsum[2] + redsum[3];
    float inv = 1.0f / s;

    uint4 o;
    unsigned ov[4];
#pragma unroll
    for (int i = 0; i < 4; ++i)
        ov[i] = (unsigned)f2bf(v[2 * i] * inv) |
                ((unsigned)f2bf(v[2 * i + 1] * inv) << 16);
    o.x = ov[0]; o.y = ov[1]; o.z = ov[2]; o.w = ov[3];
    ((uint4*)p)[tid] = o;
}

extern "C" void kernel_launch(void* const* d_in, const int* in_sizes, int n_in,
                              void* d_out, int out_size, void* d_ws, size_t ws_size,
                              hipStream_t stream) {
    const float* x  = (const float*)d_in[0];   // [4,2048,1024]
    const float* Wq = (const float*)d_in[1];   // [1024,1024]
    const float* Wk = (const float*)d_in[2];
    const float* Wv = (const float*)d_in[3];
    float* out = (float*)d_out;                // [4,2048,1024] fp32

    const int B = 4, S = 2048, D = 1024;
    const long long MS = (long long)B * S;     // 8192

    // workspace layout (bf16 elements); Sc overlays xb (xb dead after vT GEMM)
    u16* Sc  = (u16*)d_ws;                     // 4*2048*2048
    u16* xb  = Sc;                             // 8192*1024 (first half of Sc)
    u16* wqk = Sc  + (long long)B * S * S;     // 2*1024*1024
    u16* wvb = wqk + 2 * D * D;                // 1024*1024
    u16* qk  = wvb + D * D;                    // 8192*2048
    u16* vT  = qk  + MS * 2 * D;               // 1024*8192
    size_t need = (size_t)2 * ((long long)B * S * S + 3 * D * D + MS * 2 * D + MS * D);
    if (ws_size < need) return;

    hipFuncSetAttribute(reinterpret_cast<const void*>(&gemm2p<256, false>),
                        hipFuncAttributeMaxDynamicSharedMemorySize, 131072);
    hipFuncSetAttribute(reinterpret_cast<const void*>(&gemm2p<128, false>),
                        hipFuncAttributeMaxDynamicSharedMemorySize, 98304);
    hipFuncSetAttribute(reinterpret_cast<const void*>(&gemm2p<128, true>),
                        hipFuncAttributeMaxDynamicSharedMemorySize, 98304);

    // 1) converts
    cvt_bf16_kernel<<<(int)(MS * D / 8 / 256), 256, 0, stream>>>(x, xb, (int)(MS * D / 8));
    cvt_bf16_kernel<<<D * D / 8 / 256, 256, 0, stream>>>(Wq, wqk, D * D / 8);
    cvt_bf16_kernel<<<D * D / 8 / 256, 256, 0, stream>>>(Wk, wqk + D * D, D * D / 8);
    cvt_bf16_kernel<<<D * D / 8 / 256, 256, 0, stream>>>(Wv, wvb, D * D / 8);

    // 2) qk[8192][2048] = xb * [Wq;Wk]^T   (grid 8x32 = 256 blocks)
    gemm2p<256, false><<<dim3(2 * D / 256, (int)(MS / 256), 1), 512, 131072, stream>>>(
        xb, wqk, qk, D, D, 2 * D, D, 0, 0, 0);

    // 3) vT[1024][8192] = Wv * xb^T        (BN=128: grid 64x4 = 256 blocks)
    gemm2p<128, false><<<dim3((int)(MS / 128), D / 256, 1), 512, 98304, stream>>>(
        wvb, xb, vT, D, D, (int)MS, D, 0, 0, 0);

    // 4) scores Sc_b = q_b * k_b^T  (q = qk cols 0..1023, k = cols 1024..2047)
    gemm2p<256, false><<<dim3(S / 256, S / 256, B), 512, 131072, stream>>>(
        qk, qk + D, Sc, 2 * D, 2 * D, S, D,
        (long long)S * 2 * D, (long long)S * 2 * D, (long long)S * S);

    // 5) softmax rows (applies 1/32 scale)
    softmax_rows<<<(int)(B * S), 256, 0, stream>>>(Sc);

    // 6) out_b = P_b * vT_b^T  (BN=128: grid 8x8x4 = 256 blocks; fp32 out)
    gemm2p<128, true><<<dim3(D / 128, S / 256, B), 512, 98304, stream>>>(
        Sc, vT, out, S, (int)MS, D, S,
        (long long)S * S, (long long)S, (long long)S * D);
}

// Round 4
// 195.335 us; speedup vs baseline: 1.2597x; 1.0093x over previous
//
#include <hip/hip_runtime.h>
#include <hip/hip_bf16.h>

typedef unsigned short u16;
typedef __bf16 bf16x8 __attribute__((ext_vector_type(8)));
typedef float f32x4 __attribute__((ext_vector_type(4)));

#define MEMF() asm volatile("" ::: "memory")

__device__ __forceinline__ u16 f2bf(float f) {
    unsigned int u = __builtin_bit_cast(unsigned int, f);
    unsigned int r = u + 0x7FFFu + ((u >> 16) & 1u);
    return (u16)(r >> 16);
}

__device__ __forceinline__ float bf2f(unsigned int bits16) {
    return __builtin_bit_cast(float, bits16 << 16);
}

__device__ __forceinline__ void gload_lds16(const u16* g, u16* l) {
    __builtin_amdgcn_global_load_lds(
        (const __attribute__((address_space(1))) void*)(g),
        (__attribute__((address_space(3))) void*)(l), 16, 0, 0);
}

// ---------------- fp32 -> bf16 convert, 8 elems/thread ----------------
__global__ __launch_bounds__(256) void cvt_bf16_kernel(
    const float* __restrict__ in, u16* __restrict__ out, int n8)
{
    int i = blockIdx.x * 256 + threadIdx.x;
    if (i >= n8) return;
    const float4* p = (const float4*)in + 2 * (long long)i;
    float4 a = p[0], b = p[1];
    uint4 o;
    o.x = (unsigned)f2bf(a.x) | ((unsigned)f2bf(a.y) << 16);
    o.y = (unsigned)f2bf(a.z) | ((unsigned)f2bf(a.w) << 16);
    o.z = (unsigned)f2bf(b.x) | ((unsigned)f2bf(b.y) << 16);
    o.w = (unsigned)f2bf(b.z) | ((unsigned)f2bf(b.w) << 16);
    ((uint4*)out)[i] = o;
}

// ------- 4-phase/K-tile (m201-style) bf16 GEMM, C = A[M,K] * B[N,K]^T -------
// BM=256, BK=64, 512 threads = 8 waves. BN=256: waves 2x4 (128x64 each);
// BN=128: waves 4x2 (64x64 each). LDS subtiled [R][G=8][r=16][8el]: conflict-free
// ds_read_b128, linear global_load_lds. Per K-tile, 4 phases, each:
// {ds-reads for this quadrant, staged gloads (region-staggered), s_barrier,
//  lgkmcnt(0), setprio(1), MFMA quadrant, setprio(0), s_barrier}; vmcnt(4+BLOADS)
// once per tile at phase 3. XCD-bijective 2D-chunk swizzle (cw x ch per XCD).
template <int BN, bool OUT_F32>
__global__ __launch_bounds__(512, 2) void gemm4p(
    const u16* __restrict__ A, const u16* __restrict__ B, void* __restrict__ Cv,
    int lda, int ldb, int ldc, int K,
    long long sAz, long long sBz, long long sCz, int cw, int ch)
{
    constexpr int WC = (BN == 256) ? 4 : 2;        // wave grid cols
    constexpr int ROWS = (BN == 256) ? 128 : 64;   // rows per wave
    constexpr int MI = ROWS / 16;                  // A frags per wave (8 / 4)
    constexpr int MIh = MI / 2;
    constexpr int BLOADS = BN / 64;                // B gloads per thread per tile
    constexpr int BNK = BN * 64;                   // B buffer elems

    extern __shared__ u16 lds[];                   // [A buf0][A buf1][B buf0][B buf1]
    u16* ldsB = lds + 32768;

    // XCD-bijective swizzle: each XCD's resident blocks form a cw x ch rectangle.
    // requires gx%cw==0 and (gx/cw)*(gy/ch)==8 and gx*gy%8==0.
    const int flat = blockIdx.x + gridDim.x * blockIdx.y;
    const int xcd = flat & 7, jj = flat >> 3;
    const int nCx = gridDim.x / cw;
    const int bx = (xcd % nCx) * cw + jj % cw;
    const int by = (xcd / nCx) * ch + jj / cw;

    const int z = blockIdx.z;
    A += (long long)z * sAz;
    B += (long long)z * sBz;

    const int tid  = threadIdx.x;
    const int lane = tid & 63;
    const int wave = tid >> 6;
    const int wr = wave / WC, wc = wave % WC;
    const int m0 = by << 8, n0 = bx * BN;
    const int NT = K >> 6;

    // staging: slot s stages 8 contiguous bf16; row=((s>>7)<<4)|(s&15), colgrp=(s>>4)&7
    const u16* gAp[4];
    const u16* gBp[BLOADS];
#pragma unroll
    for (int i = 0; i < 4; ++i) {
        int s = tid + i * 512, row = ((s >> 7) << 4) | (s & 15), g = (s >> 4) & 7;
        gAp[i] = A + (long long)(m0 + row) * lda + g * 8;
    }
#pragma unroll
    for (int i = 0; i < BLOADS; ++i) {
        int s = tid + i * 512, row = ((s >> 7) << 4) | (s & 15), g = (s >> 4) & 7;
        gBp[i] = B + (long long)(n0 + row) * ldb + g * 8;
    }
    auto stA = [&](int kt, int buf, int i) {
        gload_lds16(gAp[i] + (long long)kt * 64, lds + buf * 16384 + (tid + i * 512) * 8);
    };
    auto stB = [&](int kt, int buf, int i) {
        gload_lds16(gBp[i] + (long long)kt * 64, ldsB + buf * BNK + (tid + i * 512) * 8);
    };

    f32x4 acc[MI][4] = {};

    // prologue: tile0 -> buf0, tile1 -> buf1; wait tile0 only
#pragma unroll
    for (int i = 0; i < 4; ++i) stA(0, 0, i);
#pragma unroll
    for (int i = 0; i < BLOADS; ++i) stB(0, 0, i);
#pragma unroll
    for (int i = 0; i < 4; ++i) stA(1, 1, i);
#pragma unroll
    for (int i = 0; i < BLOADS; ++i) stB(1, 1, i);
    if constexpr (BN == 256) asm volatile("s_waitcnt vmcnt(8)" ::: "memory");
    else                     asm volatile("s_waitcnt vmcnt(6)" ::: "memory");
    __builtin_amdgcn_s_barrier();
    MEMF();

    for (int kt = 0; kt < NT; ++kt) {
        const int cur = kt & 1;
        const u16* sAc = lds  + cur * 16384 + lane * 8;
        const u16* sBc = ldsB + cur * BNK   + lane * 8;
        const bool st = (kt + 2 < NT);

        bf16x8 a[MIh][2], b0[2][2], b1[2][2];

        // ===== phase 0: read A-lo + B-lo; MFMA Q(0,0) =====
#pragma unroll
        for (int mi = 0; mi < MIh; ++mi)
#pragma unroll
            for (int kk = 0; kk < 2; ++kk)
                a[mi][kk] = *(const bf16x8*)(sAc + ((wr * MI + mi) * 8 + kk * 4) * 128);
#pragma unroll
        for (int ni = 0; ni < 2; ++ni)
#pragma unroll
            for (int kk = 0; kk < 2; ++kk)
                b0[ni][kk] = *(const bf16x8*)(sBc + ((wc * 4 + ni) * 8 + kk * 4) * 128);
        MEMF(); __builtin_amdgcn_s_barrier();
        asm volatile("s_waitcnt lgkmcnt(0)" ::: "memory");
        __builtin_amdgcn_s_setprio(1);
#pragma unroll
        for (int kk = 0; kk < 2; ++kk)
#pragma unroll
            for (int mi = 0; mi < MIh; ++mi)
#pragma unroll
                for (int ni = 0; ni < 2; ++ni)
                    acc[mi][ni] = __builtin_amdgcn_mfma_f32_16x16x32_bf16(
                        a[mi][kk], b0[ni][kk], acc[mi][ni], 0, 0, 0);
        __builtin_amdgcn_s_setprio(0);
        MEMF(); __builtin_amdgcn_s_barrier();

        // ===== phase 1: read B-hi; stage A-lo bands; MFMA Q(0,1) =====
#pragma unroll
        for (int ni = 0; ni < 2; ++ni)
#pragma unroll
            for (int kk = 0; kk < 2; ++kk)
                b1[ni][kk] = *(const bf16x8*)(sBc + ((wc * 4 + 2 + ni) * 8 + kk * 4) * 128);
        if constexpr (BN == 256) {
            if (st) { stA(kt + 2, cur, 0); stA(kt + 2, cur, 2); }  // A-lo of wr0, wr1
        }
        MEMF(); __builtin_amdgcn_s_barrier();
        asm volatile("s_waitcnt lgkmcnt(0)" ::: "memory");
        __builtin_amdgcn_s_setprio(1);
#pragma unroll
        for (int kk = 0; kk < 2; ++kk)
#pragma unroll
            for (int mi = 0; mi < MIh; ++mi)
#pragma unroll
                for (int ni = 0; ni < 2; ++ni)
                    acc[mi][2 + ni] = __builtin_amdgcn_mfma_f32_16x16x32_bf16(
                        a[mi][kk], b1[ni][kk], acc[mi][2 + ni], 0, 0, 0);
        __builtin_amdgcn_s_setprio(0);
        MEMF(); __builtin_amdgcn_s_barrier();

        // ===== phase 2: read A-hi; stage B-lo bands; MFMA Q(1,0) =====
#pragma unroll
        for (int mi = 0; mi < MIh; ++mi)
#pragma unroll
            for (int kk = 0; kk < 2; ++kk)
                a[mi][kk] = *(const bf16x8*)(sAc + ((wr * MI + MIh + mi) * 8 + kk * 4) * 128);
        if (st) {
            if constexpr (BN == 256) { stB(kt + 2, cur, 0); stB(kt + 2, cur, 1); }
            else                     { stB(kt + 2, cur, 0); }
        }
        MEMF(); __builtin_amdgcn_s_barrier();
        asm volatile("s_waitcnt lgkmcnt(0)" ::: "memory");
        __builtin_amdgcn_s_setprio(1);
#pragma unroll
        for (int kk = 0; kk < 2; ++kk)
#pragma unroll
            for (int mi = 0; mi < MIh; ++mi)
#pragma unroll
                for (int ni = 0; ni < 2; ++ni)
                    acc[MIh + mi][ni] = __builtin_amdgcn_mfma_f32_16x16x32_bf16(
                        a[mi][kk], b0[ni][kk], acc[MIh + mi][ni], 0, 0, 0);
        __builtin_amdgcn_s_setprio(0);
        MEMF(); __builtin_amdgcn_s_barrier();

        // ===== phase 3: stage A-hi + B-hi bands; MFMA Q(1,1); counted vmcnt =====
        if (st) {
            if constexpr (BN == 256) {
                stA(kt + 2, cur, 1); stA(kt + 2, cur, 3);          // A-hi of wr0, wr1
                stB(kt + 2, cur, 2); stB(kt + 2, cur, 3);
            } else {
                stA(kt + 2, cur, 0); stA(kt + 2, cur, 1);
                stA(kt + 2, cur, 2); stA(kt + 2, cur, 3);
                stB(kt + 2, cur, 1);
            }
        }
        MEMF(); __builtin_amdgcn_s_barrier();
        __builtin_amdgcn_s_setprio(1);
#pragma unroll
        for (int kk = 0; kk < 2; ++kk)
#pragma unroll
            for (int mi = 0; mi < MIh; ++mi)
#pragma unroll
                for (int ni = 0; ni < 2; ++ni)
                    acc[MIh + mi][2 + ni] = __builtin_amdgcn_mfma_f32_16x16x32_bf16(
                        a[mi][kk], b1[ni][kk], acc[MIh + mi][2 + ni], 0, 0, 0);
        __builtin_amdgcn_s_setprio(0);
        if (st) {
            if constexpr (BN == 256) asm volatile("s_waitcnt vmcnt(8)" ::: "memory");
            else                     asm volatile("s_waitcnt vmcnt(6)" ::: "memory");
        } else if (kt + 1 < NT) {
            asm volatile("s_waitcnt vmcnt(0)" ::: "memory");
        }
        MEMF(); __builtin_amdgcn_s_barrier();
    }

    // epilogue: C/D frag layout col = lane&15, row = (lane>>4)*4+j
    const int fl = lane & 15, fg = lane >> 4;
    const int er0 = m0 + wr * ROWS + fg * 4;
    const int ec0 = n0 + wc * 64 + fl;
    if constexpr (OUT_F32) {
        float* C = (float*)Cv + (long long)z * sCz;
#pragma unroll
        for (int mi = 0; mi < MI; ++mi)
#pragma unroll
            for (int ni = 0; ni < 4; ++ni)
#pragma unroll
                for (int j = 0; j < 4; ++j)
                    C[(long long)(er0 + mi * 16 + j) * ldc + ec0 + ni * 16] = acc[mi][ni][j];
    } else {
        u16* C = (u16*)Cv + (long long)z * sCz;
#pragma unroll
        for (int mi = 0; mi < MI; ++mi)
#pragma unroll
            for (int ni = 0; ni < 4; ++ni)
#pragma unroll
                for (int j = 0; j < 4; ++j)
                    C[(long long)(er0 + mi * 16 + j) * ldc + ec0 + ni * 16] = f2bf(acc[mi][ni][j]);
    }
}

// ---------------- row softmax over 2048 bf16, in place, scale 1/32 ----------------
__global__ __launch_bounds__(256) void softmax_rows(u16* __restrict__ S)
{
    const long long row = blockIdx.x;
    u16* p = S + row * 2048;
    const int tid = threadIdx.x;
    const int lane = tid & 63, wave = tid >> 6;

    uint4 r4 = ((const uint4*)p)[tid];
    unsigned u[4] = {r4.x, r4.y, r4.z, r4.w};
    float v[8];
    const float scale = 1.0f / 32.0f;
#pragma unroll
    for (int i = 0; i < 4; ++i) {
        v[2 * i]     = bf2f(u[i] & 0xFFFFu) * scale;
        v[2 * i + 1] = __builtin_bit_cast(float, u[i] & 0xFFFF0000u) * scale;
    }
    float mx = v[0];
#pragma unroll
    for (int i = 1; i < 8; ++i) mx = fmaxf(mx, v[i]);
#pragma unroll
    for (int off = 32; off >= 1; off >>= 1) mx = fmaxf(mx, __shfl_xor(mx, off, 64));

    __shared__ float redmax[4], redsum[4];
    if (lane == 0) redmax[wave] = mx;
    __syncthreads();
    mx = fmaxf(fmaxf(redmax[0], redmax[1]), fmaxf(redmax[2], redmax[3]));

    float s = 0.f;
#pragma unroll
    for (int i = 0; i < 8; ++i) { v[i] = __expf(v[i] - mx); s += v[i]; }
#pragma unroll
    for (int off = 32; off >= 1; off >>= 1) s += __shfl_xor(s, off, 64);
    if (lane == 0) redsum[wave] = s;
    __syncthreads();
    s = redsum[0] + redsum[1] + redsum[2] + redsum[3];
    float inv = 1.0f / s;

    uint4 o;
    unsigned ov[4];
#pragma unroll
    for (int i = 0; i < 4; ++i)
        ov[i] = (unsigned)f2bf(v[2 * i] * inv) |
                ((unsigned)f2bf(v[2 * i + 1] * inv) << 16);
    o.x = ov[0]; o.y = ov[1]; o.z = ov[2]; o.w = ov[3];
    ((uint4*)p)[tid] = o;
}

extern "C" void kernel_launch(void* const* d_in, const int* in_sizes, int n_in,
                              void* d_out, int out_size, void* d_ws, size_t ws_size,
                              hipStream_t stream) {
    const float* x  = (const float*)d_in[0];   // [4,2048,1024]
    const float* Wq = (const float*)d_in[1];   // [1024,1024]
    const float* Wk = (const float*)d_in[2];
    const float* Wv = (const float*)d_in[3];
    float* out = (float*)d_out;                // [4,2048,1024] fp32

    const int B = 4, S = 2048, D = 1024;
    const long long MS = (long long)B * S;     // 8192

    // workspace layout (bf16 elements); Sc overlays xb (xb dead after vT GEMM)
    u16* Sc  = (u16*)d_ws;                     // 4*2048*2048
    u16* xb  = Sc;                             // 8192*1024 (first half of Sc)
    u16* wqk = Sc  + (long long)B * S * S;     // 2*1024*1024
    u16* wvb = wqk + 2 * D * D;                // 1024*1024
    u16* qk  = wvb + D * D;                    // 8192*2048
    u16* vT  = qk  + MS * 2 * D;               // 1024*8192
    size_t need = (size_t)2 * ((long long)B * S * S + 3 * D * D + MS * 2 * D + MS * D);
    if (ws_size < need) return;

    hipFuncSetAttribute(reinterpret_cast<const void*>(&gemm4p<256, false>),
                        hipFuncAttributeMaxDynamicSharedMemorySize, 131072);
    hipFuncSetAttribute(reinterpret_cast<const void*>(&gemm4p<128, false>),
                        hipFuncAttributeMaxDynamicSharedMemorySize, 98304);
    hipFuncSetAttribute(reinterpret_cast<const void*>(&gemm4p<128, true>),
                        hipFuncAttributeMaxDynamicSharedMemorySize, 98304);

    // 1) converts
    cvt_bf16_kernel<<<(int)(MS * D / 8 / 256), 256, 0, stream>>>(x, xb, (int)(MS * D / 8));
    cvt_bf16_kernel<<<D * D / 8 / 256, 256, 0, stream>>>(Wq, wqk, D * D / 8);
    cvt_bf16_kernel<<<D * D / 8 / 256, 256, 0, stream>>>(Wk, wqk + D * D, D * D / 8);
    cvt_bf16_kernel<<<D * D / 8 / 256, 256, 0, stream>>>(Wv, wvb, D * D / 8);

    // 2) qk[8192][2048] = xb * [Wq;Wk]^T   grid (8,32); XCD chunk 8x4
    gemm4p<256, false><<<dim3(2 * D / 256, (int)(MS / 256), 1), 512, 131072, stream>>>(
        xb, wqk, qk, D, D, 2 * D, D, 0, 0, 0, 8, 4);

    // 3) vT[1024][8192] = Wv * xb^T        grid (64,4); XCD chunk 8x4
    gemm4p<128, false><<<dim3((int)(MS / 128), D / 256, 1), 512, 98304, stream>>>(
        wvb, xb, vT, D, D, (int)MS, D, 0, 0, 0, 8, 4);

    // 4) scores Sc_b = q_b * k_b^T         grid (8,8,4); XCD chunk 2x4
    gemm4p<256, false><<<dim3(S / 256, S / 256, B), 512, 131072, stream>>>(
        qk, qk + D, Sc, 2 * D, 2 * D, S, D,
        (long long)S * 2 * D, (long long)S * 2 * D, (long long)S * S, 2, 4);

    // 5) softmax rows (applies 1/32 scale)
    softmax_rows<<<(int)(B * S), 256, 0, stream>>>(Sc);

    // 6) out_b = P_b * vT_b^T              grid (8,8,4); XCD chunk 4x2; fp32 out
    gemm4p<128, true><<<dim3(D / 128, S / 256, B), 512, 98304, stream>>>(
        Sc, vT, out, S, (int)MS, D, S,
        (long long)S * S, (long long)S, (long long)S * D, 4, 2);
}